// Round 1
// baseline (433.473 us; speedup 1.0000x reference)
//
#include <hip/hip_runtime.h>

#define NUM_GRAPHS 1024
#define D 256

// ---------------------------------------------------------------------------
// init: zero the 1024 segment sums + 1024 counts each call (harness does not
// re-poison/zero ws between replays).
// ---------------------------------------------------------------------------
__global__ void activs_init_kernel(float* __restrict__ sums, float* __restrict__ cnts) {
    int i = blockIdx.x * blockDim.x + threadIdx.x;
    if (i < NUM_GRAPHS) {
        sums[i] = 0.0f;
        cnts[i] = 0.0f;
    }
}

// ---------------------------------------------------------------------------
// main: stream input -> output copy, per-row L2 norm, run-length segment
// accumulation (batch is sorted) with one atomicAdd pair per segment-run.
// One wave (64 lanes) owns a contiguous range of rows. Per row: 64 x float4
// = 1KB = exactly one row, fully coalesced read + write.
// ---------------------------------------------------------------------------
__global__ __launch_bounds__(256) void activs_main_kernel(
        const float* __restrict__ x, const int* __restrict__ batch,
        float* __restrict__ out, float* __restrict__ sums,
        float* __restrict__ cnts, int N) {
    const int lane = threadIdx.x & 63;
    const int waveId = (blockIdx.x * blockDim.x + threadIdx.x) >> 6;
    const int totalWaves = (gridDim.x * blockDim.x) >> 6;

    const int rowsPerWave = (N + totalWaves - 1) / totalWaves;
    const int r0 = waveId * rowsPerWave;
    const int r1 = min(r0 + rowsPerWave, N);

    float runSum = 0.0f;
    float runCnt = 0.0f;
    int curSeg = -1;

    for (int r = r0; r < r1; ++r) {
        const size_t base = (size_t)r * D;
        float4 v = ((const float4*)(x + base))[lane];
        ((float4*)(out + base))[lane] = v;

        float s = v.x * v.x + v.y * v.y + v.z * v.z + v.w * v.w;
        // full 64-lane butterfly reduce
        #pragma unroll
        for (int m = 32; m; m >>= 1) s += __shfl_xor(s, m, 64);

        if (lane == 0) {
            int seg = batch[r];
            if (seg != curSeg) {
                if (runCnt > 0.0f) {
                    atomicAdd(&sums[curSeg], runSum);
                    atomicAdd(&cnts[curSeg], runCnt);
                }
                curSeg = seg;
                runSum = 0.0f;
                runCnt = 0.0f;
            }
            runSum += sqrtf(s);
            runCnt += 1.0f;
        }
    }
    if (lane == 0 && runCnt > 0.0f) {
        atomicAdd(&sums[curSeg], runSum);
        atomicAdd(&cnts[curSeg], runCnt);
    }
}

// ---------------------------------------------------------------------------
// finalize: per_graph = sum/count (0 where count==0); mask i < bmax;
// norm_mean = sum(per_graph * mask) / (bmax + 1). bmax = batch[N-1] (sorted).
// One block, 1024 threads (one per graph).
// ---------------------------------------------------------------------------
__global__ __launch_bounds__(1024) void activs_finalize_kernel(
        const float* __restrict__ sums, const float* __restrict__ cnts,
        const int* __restrict__ batch, int N, float* __restrict__ out_scalar) {
    __shared__ float red[16];
    const int i = threadIdx.x;            // 0..1023 == graph id
    const int lane = i & 63;
    const int w = i >> 6;                 // 16 waves

    const float bmax = (float)batch[N - 1];

    float c = cnts[i];
    float pg = (c > 0.0f) ? (sums[i] / c) : 0.0f;
    float val = (((float)i) < bmax) ? pg : 0.0f;

    #pragma unroll
    for (int m = 32; m; m >>= 1) val += __shfl_xor(val, m, 64);
    if (lane == 0) red[w] = val;
    __syncthreads();

    if (w == 0) {
        float v = (lane < 16) ? red[lane] : 0.0f;
        #pragma unroll
        for (int m = 8; m; m >>= 1) v += __shfl_xor(v, m, 64);
        if (lane == 0) out_scalar[0] = v / (bmax + 1.0f);
    }
}

// ---------------------------------------------------------------------------
extern "C" void kernel_launch(void* const* d_in, const int* in_sizes, int n_in,
                              void* d_out, int out_size, void* d_ws, size_t ws_size,
                              hipStream_t stream) {
    const float* x = (const float*)d_in[0];
    const int* batch = (const int*)d_in[1];
    float* out = (float*)d_out;

    const int N = in_sizes[1];                 // 1,000,000 rows (D = 256)

    float* sums = (float*)d_ws;                // [1024]
    float* cnts = sums + NUM_GRAPHS;           // [1024]

    hipLaunchKernelGGL(activs_init_kernel, dim3(4), dim3(256), 0, stream, sums, cnts);

    // 2048 blocks x 256 threads = 8192 waves; each wave owns ~123 contiguous rows.
    hipLaunchKernelGGL(activs_main_kernel, dim3(2048), dim3(256), 0, stream,
                       x, batch, out, sums, cnts, N);

    hipLaunchKernelGGL(activs_finalize_kernel, dim3(1), dim3(1024), 0, stream,
                       sums, cnts, batch, N, out + (size_t)N * D);
}

// Round 3
// 432.378 us; speedup vs baseline: 1.0025x; 1.0025x over previous
//
#include <hip/hip_runtime.h>

#define NUM_GRAPHS 1024
#define D 256

// clang native vector type — required by __builtin_nontemporal_{load,store}
// (HIP_vector_type<float,4> is a struct and is rejected).
typedef float f4 __attribute__((ext_vector_type(4)));

// ---------------------------------------------------------------------------
// init: zero the 1024 segment sums + 1024 counts each call (harness does not
// re-poison/zero ws between replays).
// ---------------------------------------------------------------------------
__global__ void activs_init_kernel(float* __restrict__ sums, float* __restrict__ cnts) {
    int i = blockIdx.x * blockDim.x + threadIdx.x;
    if (i < NUM_GRAPHS) {
        sums[i] = 0.0f;
        cnts[i] = 0.0f;
    }
}

// ---------------------------------------------------------------------------
// main: stream input -> output copy, per-row L2 norm, run-length segment
// accumulation (batch is sorted) with one atomicAdd pair per segment-run.
// One wave (64 lanes) owns a contiguous range of rows; 2-row unroll for MLP.
// Per row: 64 x float4 = 1KB = exactly one row, fully coalesced.
// Non-temporal hints: x is read-once (>L3), out is write-once (never re-read).
// ---------------------------------------------------------------------------
__global__ __launch_bounds__(256) void activs_main_kernel(
        const float* __restrict__ x, const int* __restrict__ batch,
        float* __restrict__ out, float* __restrict__ sums,
        float* __restrict__ cnts, int N) {
    const int lane = threadIdx.x & 63;
    const int waveId = (blockIdx.x * blockDim.x + threadIdx.x) >> 6;
    const int totalWaves = (gridDim.x * blockDim.x) >> 6;

    const int rowsPerWave = (N + totalWaves - 1) / totalWaves;
    const int r0 = waveId * rowsPerWave;
    const int r1 = min(r0 + rowsPerWave, N);

    float runSum = 0.0f;
    float runCnt = 0.0f;
    int curSeg = -1;

    int r = r0;
    for (; r + 1 < r1; r += 2) {
        const f4* src0 = (const f4*)(x + (size_t)r * D) + lane;
        const f4* src1 = (const f4*)(x + (size_t)(r + 1) * D) + lane;
        f4 v0 = __builtin_nontemporal_load(src0);
        f4 v1 = __builtin_nontemporal_load(src1);
        __builtin_nontemporal_store(v0, (f4*)(out + (size_t)r * D) + lane);
        __builtin_nontemporal_store(v1, (f4*)(out + (size_t)(r + 1) * D) + lane);

        float s0 = v0.x * v0.x + v0.y * v0.y + v0.z * v0.z + v0.w * v0.w;
        float s1 = v1.x * v1.x + v1.y * v1.y + v1.z * v1.z + v1.w * v1.w;
        // two independent 64-lane butterfly reduces, interleaved
        #pragma unroll
        for (int m = 32; m; m >>= 1) {
            s0 += __shfl_xor(s0, m, 64);
            s1 += __shfl_xor(s1, m, 64);
        }

        if (lane == 0) {
            int seg0 = batch[r];
            int seg1 = batch[r + 1];
            if (seg0 != curSeg) {
                if (runCnt > 0.0f) {
                    atomicAdd(&sums[curSeg], runSum);
                    atomicAdd(&cnts[curSeg], runCnt);
                }
                curSeg = seg0;
                runSum = 0.0f;
                runCnt = 0.0f;
            }
            runSum += sqrtf(s0);
            runCnt += 1.0f;
            if (seg1 != curSeg) {
                atomicAdd(&sums[curSeg], runSum);
                atomicAdd(&cnts[curSeg], runCnt);
                curSeg = seg1;
                runSum = 0.0f;
                runCnt = 0.0f;
            }
            runSum += sqrtf(s1);
            runCnt += 1.0f;
        }
    }
    // odd remainder row
    if (r < r1) {
        const f4* src = (const f4*)(x + (size_t)r * D) + lane;
        f4 v = __builtin_nontemporal_load(src);
        __builtin_nontemporal_store(v, (f4*)(out + (size_t)r * D) + lane);
        float s = v.x * v.x + v.y * v.y + v.z * v.z + v.w * v.w;
        #pragma unroll
        for (int m = 32; m; m >>= 1) s += __shfl_xor(s, m, 64);
        if (lane == 0) {
            int seg = batch[r];
            if (seg != curSeg) {
                if (runCnt > 0.0f) {
                    atomicAdd(&sums[curSeg], runSum);
                    atomicAdd(&cnts[curSeg], runCnt);
                }
                curSeg = seg;
                runSum = 0.0f;
                runCnt = 0.0f;
            }
            runSum += sqrtf(s);
            runCnt += 1.0f;
        }
    }
    if (lane == 0 && runCnt > 0.0f) {
        atomicAdd(&sums[curSeg], runSum);
        atomicAdd(&cnts[curSeg], runCnt);
    }
}

// ---------------------------------------------------------------------------
// finalize: per_graph = sum/count (0 where count==0); mask i < bmax;
// norm_mean = sum(per_graph * mask) / (bmax + 1). bmax = batch[N-1] (sorted).
// One block, 1024 threads (one per graph).
// ---------------------------------------------------------------------------
__global__ __launch_bounds__(1024) void activs_finalize_kernel(
        const float* __restrict__ sums, const float* __restrict__ cnts,
        const int* __restrict__ batch, int N, float* __restrict__ out_scalar) {
    __shared__ float red[16];
    const int i = threadIdx.x;            // 0..1023 == graph id
    const int lane = i & 63;
    const int w = i >> 6;                 // 16 waves

    const float bmax = (float)batch[N - 1];

    float c = cnts[i];
    float pg = (c > 0.0f) ? (sums[i] / c) : 0.0f;
    float val = (((float)i) < bmax) ? pg : 0.0f;

    #pragma unroll
    for (int m = 32; m; m >>= 1) val += __shfl_xor(val, m, 64);
    if (lane == 0) red[w] = val;
    __syncthreads();

    if (w == 0) {
        float v = (lane < 16) ? red[lane] : 0.0f;
        #pragma unroll
        for (int m = 8; m; m >>= 1) v += __shfl_xor(v, m, 64);
        if (lane == 0) out_scalar[0] = v / (bmax + 1.0f);
    }
}

// ---------------------------------------------------------------------------
extern "C" void kernel_launch(void* const* d_in, const int* in_sizes, int n_in,
                              void* d_out, int out_size, void* d_ws, size_t ws_size,
                              hipStream_t stream) {
    const float* x = (const float*)d_in[0];
    const int* batch = (const int*)d_in[1];
    float* out = (float*)d_out;

    const int N = in_sizes[1];                 // 1,000,000 rows (D = 256)

    float* sums = (float*)d_ws;                // [1024]
    float* cnts = sums + NUM_GRAPHS;           // [1024]

    hipLaunchKernelGGL(activs_init_kernel, dim3(4), dim3(256), 0, stream, sums, cnts);

    // 2048 blocks x 256 threads = 8192 waves; each wave owns ~123 contiguous rows.
    hipLaunchKernelGGL(activs_main_kernel, dim3(2048), dim3(256), 0, stream,
                       x, batch, out, sums, cnts, N);

    hipLaunchKernelGGL(activs_finalize_kernel, dim3(1), dim3(1024), 0, stream,
                       sums, cnts, batch, N, out + (size_t)N * D);
}

// Round 4
// 432.341 us; speedup vs baseline: 1.0026x; 1.0001x over previous
//
#include <hip/hip_runtime.h>

#define NUM_GRAPHS 1024
#define D 256

// ---------------------------------------------------------------------------
// init: zero the 1024 segment sums + 1024 counts each call (harness does not
// re-poison/zero ws between replays).
// ---------------------------------------------------------------------------
__global__ void activs_init_kernel(float* __restrict__ sums, float* __restrict__ cnts) {
    int i = blockIdx.x * blockDim.x + threadIdx.x;
    if (i < NUM_GRAPHS) {
        sums[i] = 0.0f;
        cnts[i] = 0.0f;
    }
}

// ---------------------------------------------------------------------------
// main: stream input -> output copy, per-row L2 norm, run-length segment
// accumulation (batch is sorted, each wave visits rows in ascending order).
//
// Mapping (dense-front): each BLOCK owns a contiguous chunk of rows; the 4
// waves of the block interleave rows (wave j: start+j, start+j+4, ...), so
// the block's instantaneous footprint is a dense 4KB window advancing
// sequentially -> 2048 dense streams instead of 8192 scattered ones.
// Per row: 64 lanes x float4 = 1KB, fully coalesced. 2-row unroll for MLP.
// ---------------------------------------------------------------------------
__global__ __launch_bounds__(256) void activs_main_kernel(
        const float* __restrict__ x, const int* __restrict__ batch,
        float* __restrict__ out, float* __restrict__ sums,
        float* __restrict__ cnts, int N) {
    const int lane = threadIdx.x & 63;
    const int waveInBlock = threadIdx.x >> 6;        // 0..3
    const int numBlocks = gridDim.x;

    const int rowsPerBlock = (N + numBlocks - 1) / numBlocks;
    const int rowStart = blockIdx.x * rowsPerBlock;
    const int rowEnd = min(rowStart + rowsPerBlock, N);

    float runSum = 0.0f;
    float runCnt = 0.0f;
    int curSeg = -1;

    int r = rowStart + waveInBlock;

    // 2-row unroll: rows r and r+4 (both owned by this wave)
    for (; r + 4 < rowEnd; r += 8) {
        const float4 v0 = ((const float4*)(x + (size_t)r * D))[lane];
        const float4 v1 = ((const float4*)(x + (size_t)(r + 4) * D))[lane];
        ((float4*)(out + (size_t)r * D))[lane] = v0;
        ((float4*)(out + (size_t)(r + 4) * D))[lane] = v1;

        float s0 = v0.x * v0.x + v0.y * v0.y + v0.z * v0.z + v0.w * v0.w;
        float s1 = v1.x * v1.x + v1.y * v1.y + v1.z * v1.z + v1.w * v1.w;
        #pragma unroll
        for (int m = 32; m; m >>= 1) {
            s0 += __shfl_xor(s0, m, 64);
            s1 += __shfl_xor(s1, m, 64);
        }

        if (lane == 0) {
            const int seg0 = batch[r];
            const int seg1 = batch[r + 4];
            if (seg0 != curSeg) {
                if (runCnt > 0.0f) {
                    atomicAdd(&sums[curSeg], runSum);
                    atomicAdd(&cnts[curSeg], runCnt);
                }
                curSeg = seg0;
                runSum = 0.0f;
                runCnt = 0.0f;
            }
            runSum += sqrtf(s0);
            runCnt += 1.0f;
            if (seg1 != curSeg) {
                atomicAdd(&sums[curSeg], runSum);
                atomicAdd(&cnts[curSeg], runCnt);
                curSeg = seg1;
                runSum = 0.0f;
                runCnt = 0.0f;
            }
            runSum += sqrtf(s1);
            runCnt += 1.0f;
        }
    }
    // remainder rows (stride 4)
    for (; r < rowEnd; r += 4) {
        const float4 v = ((const float4*)(x + (size_t)r * D))[lane];
        ((float4*)(out + (size_t)r * D))[lane] = v;
        float s = v.x * v.x + v.y * v.y + v.z * v.z + v.w * v.w;
        #pragma unroll
        for (int m = 32; m; m >>= 1) s += __shfl_xor(s, m, 64);
        if (lane == 0) {
            const int seg = batch[r];
            if (seg != curSeg) {
                if (runCnt > 0.0f) {
                    atomicAdd(&sums[curSeg], runSum);
                    atomicAdd(&cnts[curSeg], runCnt);
                }
                curSeg = seg;
                runSum = 0.0f;
                runCnt = 0.0f;
            }
            runSum += sqrtf(s);
            runCnt += 1.0f;
        }
    }
    if (lane == 0 && runCnt > 0.0f) {
        atomicAdd(&sums[curSeg], runSum);
        atomicAdd(&cnts[curSeg], runCnt);
    }
}

// ---------------------------------------------------------------------------
// finalize: per_graph = sum/count (0 where count==0); mask i < bmax;
// norm_mean = sum(per_graph * mask) / (bmax + 1). bmax = batch[N-1] (sorted).
// One block, 1024 threads (one per graph).
// ---------------------------------------------------------------------------
__global__ __launch_bounds__(1024) void activs_finalize_kernel(
        const float* __restrict__ sums, const float* __restrict__ cnts,
        const int* __restrict__ batch, int N, float* __restrict__ out_scalar) {
    __shared__ float red[16];
    const int i = threadIdx.x;            // 0..1023 == graph id
    const int lane = i & 63;
    const int w = i >> 6;                 // 16 waves

    const float bmax = (float)batch[N - 1];

    float c = cnts[i];
    float pg = (c > 0.0f) ? (sums[i] / c) : 0.0f;
    float val = (((float)i) < bmax) ? pg : 0.0f;

    #pragma unroll
    for (int m = 32; m; m >>= 1) val += __shfl_xor(val, m, 64);
    if (lane == 0) red[w] = val;
    __syncthreads();

    if (w == 0) {
        float v = (lane < 16) ? red[lane] : 0.0f;
        #pragma unroll
        for (int m = 8; m; m >>= 1) v += __shfl_xor(v, m, 64);
        if (lane == 0) out_scalar[0] = v / (bmax + 1.0f);
    }
}

// ---------------------------------------------------------------------------
extern "C" void kernel_launch(void* const* d_in, const int* in_sizes, int n_in,
                              void* d_out, int out_size, void* d_ws, size_t ws_size,
                              hipStream_t stream) {
    const float* x = (const float*)d_in[0];
    const int* batch = (const int*)d_in[1];
    float* out = (float*)d_out;

    const int N = in_sizes[1];                 // 1,000,000 rows (D = 256)

    float* sums = (float*)d_ws;                // [1024]
    float* cnts = sums + NUM_GRAPHS;           // [1024]

    hipLaunchKernelGGL(activs_init_kernel, dim3(4), dim3(256), 0, stream, sums, cnts);

    // 2048 blocks x 256 threads; each block streams a dense ~489-row chunk.
    hipLaunchKernelGGL(activs_main_kernel, dim3(2048), dim3(256), 0, stream,
                       x, batch, out, sums, cnts, N);

    hipLaunchKernelGGL(activs_finalize_kernel, dim3(1), dim3(1024), 0, stream,
                       sums, cnts, batch, N, out + (size_t)N * D);
}

// Round 5
// 427.333 us; speedup vs baseline: 1.0144x; 1.0117x over previous
//
#include <hip/hip_runtime.h>

#define NUM_GRAPHS 1024
#define D 256

// ---------------------------------------------------------------------------
// init: zero the 1024 segment sums + 1024 counts each call (harness does not
// re-poison/zero ws between replays).
// ---------------------------------------------------------------------------
__global__ void activs_init_kernel(float* __restrict__ sums, float* __restrict__ cnts) {
    int i = blockIdx.x * blockDim.x + threadIdx.x;
    if (i < NUM_GRAPHS) {
        sums[i] = 0.0f;
        cnts[i] = 0.0f;
    }
}

__device__ __forceinline__ float sq4(const float4 v) {
    return v.x * v.x + v.y * v.y + v.z * v.z + v.w * v.w;
}

// ---------------------------------------------------------------------------
// main: quarter-wave rows. 16 lanes own one row (lane l reads float4s
// l, l+16, l+32, l+48 of its row); a wave processes 8 rows/iteration
// (2 quads of 4) -> 8KB read + 8KB write in flight per wave. Reduce is a
// 4-step __shfl_xor within the 16-lane group; sqrt uniform on all lanes;
// lane 0 run-length-aggregates the 8 consecutive rows (batch is sorted)
// and flushes once per segment-run via atomicAdd.
// ---------------------------------------------------------------------------
__global__ __launch_bounds__(256) void activs_main_kernel(
        const float* __restrict__ x, const int* __restrict__ batch,
        float* __restrict__ out, float* __restrict__ sums,
        float* __restrict__ cnts, int N) {
    const int lane = threadIdx.x & 63;
    const int q = lane >> 4;          // 0..3: which row of the quad
    const int l = lane & 15;          // 0..15: position within the row
    const int waveId = (blockIdx.x * blockDim.x + threadIdx.x) >> 6;
    const int totalWaves = (gridDim.x * blockDim.x) >> 6;

    const int Nq = N & ~7;            // multiple-of-8 prefix (N=1e6 -> Nq==N)

    for (int r0 = waveId * 8; r0 < Nq; r0 += totalWaves * 8) {
        const float4* srcA = (const float4*)(x + (size_t)(r0 + q) * D);
        const float4* srcB = (const float4*)(x + (size_t)(r0 + 4 + q) * D);
        float4* dstA = (float4*)(out + (size_t)(r0 + q) * D);
        float4* dstB = (float4*)(out + (size_t)(r0 + 4 + q) * D);

        // 8 independent 16B loads per lane = 128B/lane in flight
        float4 a0 = srcA[l];
        float4 a1 = srcA[l + 16];
        float4 a2 = srcA[l + 32];
        float4 a3 = srcA[l + 48];
        float4 b0 = srcB[l];
        float4 b1 = srcB[l + 16];
        float4 b2 = srcB[l + 32];
        float4 b3 = srcB[l + 48];

        dstA[l]      = a0;
        dstA[l + 16] = a1;
        dstA[l + 32] = a2;
        dstA[l + 48] = a3;
        dstB[l]      = b0;
        dstB[l + 16] = b1;
        dstB[l + 32] = b2;
        dstB[l + 48] = b3;

        float sA = sq4(a0) + sq4(a1) + sq4(a2) + sq4(a3);
        float sB = sq4(b0) + sq4(b1) + sq4(b2) + sq4(b3);
        // 4-step butterfly within each 16-lane group (two chains interleaved)
        #pragma unroll
        for (int m = 1; m <= 8; m <<= 1) {
            sA += __shfl_xor(sA, m, 64);
            sB += __shfl_xor(sB, m, 64);
        }
        sA = sqrtf(sA);               // every lane of the group holds the sum
        sB = sqrtf(sB);

        // gather the 8 row norms to all lanes (8 independent shuffles)
        float n0 = __shfl(sA, 0, 64), n1 = __shfl(sA, 16, 64);
        float n2 = __shfl(sA, 32, 64), n3 = __shfl(sA, 48, 64);
        float n4 = __shfl(sB, 0, 64), n5 = __shfl(sB, 16, 64);
        float n6 = __shfl(sB, 32, 64), n7 = __shfl(sB, 48, 64);

        if (lane == 0) {
            float n[8] = {n0, n1, n2, n3, n4, n5, n6, n7};
            const int4 w0 = ((const int4*)(batch + r0))[0];
            const int4 w1 = ((const int4*)(batch + r0))[1];
            const int b[8] = {w0.x, w0.y, w0.z, w0.w, w1.x, w1.y, w1.z, w1.w};
            int seg = b[0];
            float rs = n[0], rc = 1.0f;
            #pragma unroll
            for (int k = 1; k < 8; ++k) {
                if (b[k] == seg) { rs += n[k]; rc += 1.0f; }
                else {
                    atomicAdd(&sums[seg], rs);
                    atomicAdd(&cnts[seg], rc);
                    seg = b[k]; rs = n[k]; rc = 1.0f;
                }
            }
            atomicAdd(&sums[seg], rs);
            atomicAdd(&cnts[seg], rc);
        }
    }

    // tail rows (only if N % 8 != 0; dead for N=1e6): wave 0, 64 lanes/row
    if (waveId == 0) {
        for (int r = Nq; r < N; ++r) {
            const float4 v = ((const float4*)(x + (size_t)r * D))[lane];
            ((float4*)(out + (size_t)r * D))[lane] = v;
            float s = sq4(v);
            #pragma unroll
            for (int m = 32; m; m >>= 1) s += __shfl_xor(s, m, 64);
            if (lane == 0) {
                atomicAdd(&sums[batch[r]], sqrtf(s));
                atomicAdd(&cnts[batch[r]], 1.0f);
            }
        }
    }
}

// ---------------------------------------------------------------------------
// finalize: per_graph = sum/count (0 where count==0); mask i < bmax;
// norm_mean = sum(per_graph * mask) / (bmax + 1). bmax = batch[N-1] (sorted).
// One block, 1024 threads (one per graph).
// ---------------------------------------------------------------------------
__global__ __launch_bounds__(1024) void activs_finalize_kernel(
        const float* __restrict__ sums, const float* __restrict__ cnts,
        const int* __restrict__ batch, int N, float* __restrict__ out_scalar) {
    __shared__ float red[16];
    const int i = threadIdx.x;            // 0..1023 == graph id
    const int lane = i & 63;
    const int w = i >> 6;                 // 16 waves

    const float bmax = (float)batch[N - 1];

    float c = cnts[i];
    float pg = (c > 0.0f) ? (sums[i] / c) : 0.0f;
    float val = (((float)i) < bmax) ? pg : 0.0f;

    #pragma unroll
    for (int m = 32; m; m >>= 1) val += __shfl_xor(val, m, 64);
    if (lane == 0) red[w] = val;
    __syncthreads();

    if (w == 0) {
        float v = (lane < 16) ? red[lane] : 0.0f;
        #pragma unroll
        for (int m = 8; m; m >>= 1) v += __shfl_xor(v, m, 64);
        if (lane == 0) out_scalar[0] = v / (bmax + 1.0f);
    }
}

// ---------------------------------------------------------------------------
extern "C" void kernel_launch(void* const* d_in, const int* in_sizes, int n_in,
                              void* d_out, int out_size, void* d_ws, size_t ws_size,
                              hipStream_t stream) {
    const float* x = (const float*)d_in[0];
    const int* batch = (const int*)d_in[1];
    float* out = (float*)d_out;

    const int N = in_sizes[1];                 // 1,000,000 rows (D = 256)

    float* sums = (float*)d_ws;                // [1024]
    float* cnts = sums + NUM_GRAPHS;           // [1024]

    hipLaunchKernelGGL(activs_init_kernel, dim3(4), dim3(256), 0, stream, sums, cnts);

    // 2048 blocks x 256 threads = 8192 waves; dense global front of
    // 65536 rows (64MB) advancing per iteration.
    hipLaunchKernelGGL(activs_main_kernel, dim3(2048), dim3(256), 0, stream,
                       x, batch, out, sums, cnts, N);

    hipLaunchKernelGGL(activs_finalize_kernel, dim3(1), dim3(1024), 0, stream,
                       sums, cnts, batch, N, out + (size_t)N * D);
}

// Round 6
// 413.991 us; speedup vs baseline: 1.0471x; 1.0322x over previous
//
#include <hip/hip_runtime.h>

#define NUM_GRAPHS 1024
#define D 256

// ---------------------------------------------------------------------------
// init: zero the 1024 segment sums + 1024 counts each call.
// ---------------------------------------------------------------------------
__global__ void activs_init_kernel(float* __restrict__ sums, float* __restrict__ cnts) {
    int i = blockIdx.x * blockDim.x + threadIdx.x;
    if (i < NUM_GRAPHS) {
        sums[i] = 0.0f;
        cnts[i] = 0.0f;
    }
}

__device__ __forceinline__ float sq4(const float4 v) {
    return v.x * v.x + v.y * v.y + v.z * v.z + v.w * v.w;
}

struct Rows {
    float4 a0, a1, a2, a3;   // row r0+q
    float4 b0, b1, b2, b3;   // row r0+4+q
};

__device__ __forceinline__ void load_rows(Rows& R, const float* __restrict__ x,
                                          int r0, int q, int l) {
    const float4* srcA = (const float4*)(x + (size_t)(r0 + q) * D);
    const float4* srcB = (const float4*)(x + (size_t)(r0 + 4 + q) * D);
    R.a0 = srcA[l];
    R.a1 = srcA[l + 16];
    R.a2 = srcA[l + 32];
    R.a3 = srcA[l + 48];
    R.b0 = srcB[l];
    R.b1 = srcB[l + 16];
    R.b2 = srcB[l + 32];
    R.b3 = srcB[l + 48];
}

__device__ __forceinline__ void store_rows(const Rows& R, float* __restrict__ out,
                                           int r0, int q, int l) {
    float4* dstA = (float4*)(out + (size_t)(r0 + q) * D);
    float4* dstB = (float4*)(out + (size_t)(r0 + 4 + q) * D);
    dstA[l]      = R.a0;
    dstA[l + 16] = R.a1;
    dstA[l + 32] = R.a2;
    dstA[l + 48] = R.a3;
    dstB[l]      = R.b0;
    dstB[l + 16] = R.b1;
    dstB[l + 32] = R.b2;
    dstB[l + 48] = R.b3;
}

// ---------------------------------------------------------------------------
// main: quarter-wave rows (16 lanes per row, 8 rows per wave-iteration),
// software-pipelined: iteration i+1's 8 row-loads + batch words are issued
// BEFORE iteration i's stores/reduce, so every wave keeps ~8 VMEM ops in
// flight through the reduce/serial tail (vmcnt(8)-style wait, not vmcnt(0)).
// batch is sorted; lane 0 run-length-aggregates 8 consecutive rows and
// flushes one atomicAdd pair per segment-run.
// ---------------------------------------------------------------------------
__global__ __launch_bounds__(256) void activs_main_kernel(
        const float* __restrict__ x, const int* __restrict__ batch,
        float* __restrict__ out, float* __restrict__ sums,
        float* __restrict__ cnts, int N) {
    const int lane = threadIdx.x & 63;
    const int q = lane >> 4;          // 0..3: which row of the quad
    const int l = lane & 15;          // 0..15: position within the row
    const int waveId = (blockIdx.x * blockDim.x + threadIdx.x) >> 6;
    const int totalWaves = (gridDim.x * blockDim.x) >> 6;
    const int stride = totalWaves * 8;

    const int Nq = N & ~7;            // multiple-of-8 prefix (N=1e6 -> Nq==N)

    int r = waveId * 8;
    if (r < Nq) {
        Rows cur;
        load_rows(cur, x, r, q, l);
        // batch words for current group, loaded by all lanes (same address ->
        // single merged request; keeps them out of the lane-0 serial section)
        int4 w0 = ((const int4*)(batch + r))[0];
        int4 w1 = ((const int4*)(batch + r))[1];

        while (true) {
            const int rn = r + stride;
            const bool more = (rn < Nq);
            Rows nxt;
            int4 nw0, nw1;
            if (more) {
                load_rows(nxt, x, rn, q, l);      // prefetch: stays in flight
                nw0 = ((const int4*)(batch + rn))[0];
                nw1 = ((const int4*)(batch + rn))[1];
            }

            store_rows(cur, out, r, q, l);        // waits cur loads only

            float sA = sq4(cur.a0) + sq4(cur.a1) + sq4(cur.a2) + sq4(cur.a3);
            float sB = sq4(cur.b0) + sq4(cur.b1) + sq4(cur.b2) + sq4(cur.b3);
            #pragma unroll
            for (int m = 1; m <= 8; m <<= 1) {
                sA += __shfl_xor(sA, m, 64);
                sB += __shfl_xor(sB, m, 64);
            }
            sA = sqrtf(sA);
            sB = sqrtf(sB);

            const float n0 = __shfl(sA, 0, 64), n1 = __shfl(sA, 16, 64);
            const float n2 = __shfl(sA, 32, 64), n3 = __shfl(sA, 48, 64);
            const float n4 = __shfl(sB, 0, 64), n5 = __shfl(sB, 16, 64);
            const float n6 = __shfl(sB, 32, 64), n7 = __shfl(sB, 48, 64);

            if (lane == 0) {
                const float n[8] = {n0, n1, n2, n3, n4, n5, n6, n7};
                const int b[8] = {w0.x, w0.y, w0.z, w0.w, w1.x, w1.y, w1.z, w1.w};
                int seg = b[0];
                float rs = n[0], rc = 1.0f;
                #pragma unroll
                for (int k = 1; k < 8; ++k) {
                    if (b[k] == seg) { rs += n[k]; rc += 1.0f; }
                    else {
                        atomicAdd(&sums[seg], rs);
                        atomicAdd(&cnts[seg], rc);
                        seg = b[k]; rs = n[k]; rc = 1.0f;
                    }
                }
                atomicAdd(&sums[seg], rs);
                atomicAdd(&cnts[seg], rc);
            }

            if (!more) break;
            cur = nxt;
            w0 = nw0;
            w1 = nw1;
            r = rn;
        }
    }

    // tail rows (only if N % 8 != 0; dead for N=1e6): wave 0, 64 lanes/row
    if (waveId == 0) {
        for (int t = Nq; t < N; ++t) {
            const float4 v = ((const float4*)(x + (size_t)t * D))[lane];
            ((float4*)(out + (size_t)t * D))[lane] = v;
            float s = sq4(v);
            #pragma unroll
            for (int m = 32; m; m >>= 1) s += __shfl_xor(s, m, 64);
            if (lane == 0) {
                atomicAdd(&sums[batch[t]], sqrtf(s));
                atomicAdd(&cnts[batch[t]], 1.0f);
            }
        }
    }
}

// ---------------------------------------------------------------------------
// finalize: per_graph = sum/count (0 where count==0); mask i < bmax;
// norm_mean = sum(per_graph * mask) / (bmax + 1). bmax = batch[N-1] (sorted).
// ---------------------------------------------------------------------------
__global__ __launch_bounds__(1024) void activs_finalize_kernel(
        const float* __restrict__ sums, const float* __restrict__ cnts,
        const int* __restrict__ batch, int N, float* __restrict__ out_scalar) {
    __shared__ float red[16];
    const int i = threadIdx.x;            // 0..1023 == graph id
    const int lane = i & 63;
    const int w = i >> 6;                 // 16 waves

    const float bmax = (float)batch[N - 1];

    float c = cnts[i];
    float pg = (c > 0.0f) ? (sums[i] / c) : 0.0f;
    float val = (((float)i) < bmax) ? pg : 0.0f;

    #pragma unroll
    for (int m = 32; m; m >>= 1) val += __shfl_xor(val, m, 64);
    if (lane == 0) red[w] = val;
    __syncthreads();

    if (w == 0) {
        float v = (lane < 16) ? red[lane] : 0.0f;
        #pragma unroll
        for (int m = 8; m; m >>= 1) v += __shfl_xor(v, m, 64);
        if (lane == 0) out_scalar[0] = v / (bmax + 1.0f);
    }
}

// ---------------------------------------------------------------------------
extern "C" void kernel_launch(void* const* d_in, const int* in_sizes, int n_in,
                              void* d_out, int out_size, void* d_ws, size_t ws_size,
                              hipStream_t stream) {
    const float* x = (const float*)d_in[0];
    const int* batch = (const int*)d_in[1];
    float* out = (float*)d_out;

    const int N = in_sizes[1];                 // 1,000,000 rows (D = 256)

    float* sums = (float*)d_ws;                // [1024]
    float* cnts = sums + NUM_GRAPHS;           // [1024]

    hipLaunchKernelGGL(activs_init_kernel, dim3(4), dim3(256), 0, stream, sums, cnts);

    hipLaunchKernelGGL(activs_main_kernel, dim3(2048), dim3(256), 0, stream,
                       x, batch, out, sums, cnts, N);

    hipLaunchKernelGGL(activs_finalize_kernel, dim3(1), dim3(1024), 0, stream,
                       sums, cnts, batch, N, out + (size_t)N * D);
}